// Round 1
// baseline (1075.010 us; speedup 1.0000x reference)
//
#include <hip/hip_runtime.h>
#include <hip/hip_bf16.h>
#include <cstdint>

// ---------------------------------------------------------------------------
// GAT 2-layer model on MI355X.
// Pipeline:
//   CSR build (deg -> scan -> scatter)   [graph shared by both layers]
//   L1: gemm(x@W1) -> al -> logits -> aggr(+b1,ELU) -> h1e
//   L2: gemm(h1e@W2) -> al -> logits -> aggr(+b2,ELU, fused mean-pool accum)
//   final: pooled/cnt @ Wfc + bfc
// ---------------------------------------------------------------------------

__device__ __forceinline__ float wave_reduce_sum(float v) {
#pragma unroll
  for (int off = 32; off > 0; off >>= 1) v += __shfl_xor(v, off, 64);
  return v;
}
__device__ __forceinline__ float wave_reduce_max(float v) {
#pragma unroll
  for (int off = 32; off > 0; off >>= 1) v = fmaxf(v, __shfl_xor(v, off, 64));
  return v;
}

// ---------------- CSR build ----------------

__global__ void deg_kernel(const int* __restrict__ ei, int E, int N,
                           int* __restrict__ deg) {
  int t = blockIdx.x * blockDim.x + threadIdx.x;
  int total = E + N;
  if (t >= total) return;
  int d = (t < E) ? ei[E + t] : (t - E);  // self loops appended
  atomicAdd(&deg[d], 1);
}

// block scans 2048 elements (256 threads x 8)
__global__ void scan1_kernel(const int* __restrict__ deg, int* __restrict__ rowptr,
                             int* __restrict__ partials, int n) {
  __shared__ int wsum[4];
  int t = threadIdx.x;
  int lane = t & 63, wv = t >> 6;
  int base = blockIdx.x * 2048 + t * 8;
  int v[8];
  int s = 0;
#pragma unroll
  for (int i = 0; i < 8; i++) {
    int idx = base + i;
    v[i] = (idx < n) ? deg[idx] : 0;
    s += v[i];
  }
  int x = s;
#pragma unroll
  for (int off = 1; off < 64; off <<= 1) {
    int u = __shfl_up(x, off, 64);
    if (lane >= off) x += u;
  }
  if (lane == 63) wsum[wv] = x;
  __syncthreads();
  int woff = 0;
  for (int j = 0; j < wv; j++) woff += wsum[j];
  int excl = woff + x - s;
#pragma unroll
  for (int i = 0; i < 8; i++) {
    int idx = base + i;
    if (idx < n) rowptr[idx] = excl;
    excl += v[i];
  }
  if (t == 255) partials[blockIdx.x] = woff + x;  // block total
}

__global__ void scan2_kernel(int* __restrict__ partials, int nb,
                             int* __restrict__ rowptr_end) {
  if (threadIdx.x == 0 && blockIdx.x == 0) {
    int run = 0;
    for (int i = 0; i < nb; i++) {
      int t = partials[i];
      partials[i] = run;
      run += t;
    }
    *rowptr_end = run;
  }
}

__global__ void scan3_kernel(int* __restrict__ rowptr, const int* __restrict__ partials,
                             int n) {
  int idx = blockIdx.x * blockDim.x + threadIdx.x;
  if (idx < n) rowptr[idx] += partials[idx >> 11];
}

__global__ void scatter_kernel(const int* __restrict__ ei, int E, int N,
                               int* __restrict__ cursor, int* __restrict__ csrc,
                               int* __restrict__ cdst) {
  int t = blockIdx.x * blockDim.x + threadIdx.x;
  int total = E + N;
  if (t >= total) return;
  int s, d;
  if (t < E) {
    s = ei[t];
    d = ei[E + t];
  } else {
    s = d = t - E;
  }
  int pos = atomicAdd(&cursor[d], 1);
  csrc[pos] = s;
  cdst[pos] = d;
}

// ---------------- dense compute ----------------

// C[N][64] = A[N][KDIM] @ W[KDIM][64], fp32, 64x64 tile, 4x4 microtile
template <int KDIM>
__global__ __launch_bounds__(256) void gemm64(const float* __restrict__ A,
                                              const float* __restrict__ W,
                                              float* __restrict__ C, int N) {
  __shared__ float As[32][68];  // transposed: As[k][node]
  __shared__ float Ws[32][68];  // Ws[k][col]
  const int block_m = blockIdx.x * 64;
  const int t = threadIdx.x;  // 0..255
  const int tc = t & 15;      // col group
  const int tr = t >> 4;      // node group
  const int c0 = tc * 4, r0 = tr * 4;
  float acc[4][4] = {};

  for (int kc = 0; kc < KDIM; kc += 32) {
    // A chunk: 64 nodes x 32 k  (512 float4, 8 float4 per node-row segment)
    for (int q = t; q < 512; q += 256) {
      int node = q >> 3, f4 = q & 7;
      int gn = block_m + node;
      if (gn >= N) gn = N - 1;  // clamp (stores are guarded)
      const float4 v = *(const float4*)(A + (size_t)gn * KDIM + kc + f4 * 4);
      As[f4 * 4 + 0][node] = v.x;
      As[f4 * 4 + 1][node] = v.y;
      As[f4 * 4 + 2][node] = v.z;
      As[f4 * 4 + 3][node] = v.w;
    }
    // W chunk: 32 k x 64 cols (512 float4, 16 float4 per row)
    for (int q = t; q < 512; q += 256) {
      int k = q >> 4, f4 = q & 15;
      const float4 v = *(const float4*)(W + (size_t)(kc + k) * 64 + f4 * 4);
      *(float4*)&Ws[k][f4 * 4] = v;
    }
    __syncthreads();
#pragma unroll
    for (int k = 0; k < 32; ++k) {
      float4 a = *(const float4*)&As[k][r0];
      float4 b = *(const float4*)&Ws[k][c0];
      acc[0][0] += a.x * b.x; acc[0][1] += a.x * b.y; acc[0][2] += a.x * b.z; acc[0][3] += a.x * b.w;
      acc[1][0] += a.y * b.x; acc[1][1] += a.y * b.y; acc[1][2] += a.y * b.z; acc[1][3] += a.y * b.w;
      acc[2][0] += a.z * b.x; acc[2][1] += a.z * b.y; acc[2][2] += a.z * b.z; acc[2][3] += a.z * b.w;
      acc[3][0] += a.w * b.x; acc[3][1] += a.w * b.y; acc[3][2] += a.w * b.z; acc[3][3] += a.w * b.w;
    }
    __syncthreads();
  }
#pragma unroll
  for (int i = 0; i < 4; ++i) {
    int gn = block_m + r0 + i;
    if (gn < N) {
      float4 v = make_float4(acc[i][0], acc[i][1], acc[i][2], acc[i][3]);
      *(float4*)(C + (size_t)gn * 64 + c0) = v;
    }
  }
}

// al_src[n] = h[n,:] . a_src ; al_dst[n] = h[n,:] . a_dst   (wave per node)
__global__ void al_kernel(const float* __restrict__ h, const float* __restrict__ a_src,
                          const float* __restrict__ a_dst, float* __restrict__ alsrc,
                          float* __restrict__ aldst, int N) {
  int wid = (blockIdx.x * blockDim.x + threadIdx.x) >> 6;
  int lane = threadIdx.x & 63;
  if (wid >= N) return;
  float v = h[(size_t)wid * 64 + lane];
  float s1 = wave_reduce_sum(v * a_src[lane]);
  float s2 = wave_reduce_sum(v * a_dst[lane]);
  if (lane == 0) {
    alsrc[wid] = s1;
    aldst[wid] = s2;
  }
}

__global__ void logits_kernel(const int* __restrict__ csrc, const int* __restrict__ cdst,
                              const float* __restrict__ alsrc, const float* __restrict__ aldst,
                              float* __restrict__ logit, int M) {
  int t = blockIdx.x * blockDim.x + threadIdx.x;
  if (t >= M) return;
  float e = alsrc[csrc[t]] + aldst[cdst[t]];
  logit[t] = (e > 0.f) ? e : 0.2f * e;  // leaky_relu 0.2
}

// One wave per destination node: softmax over incoming edges + weighted aggregate.
// lane = feature. do_pool: fused global-mean-pool accumulation (layer 2).
__global__ void aggr_kernel(const int* __restrict__ rowptr, const int* __restrict__ csrc,
                            const float* __restrict__ logit, const float* __restrict__ h,
                            const float* __restrict__ bias, float* __restrict__ out,
                            int N, int do_pool, const int* __restrict__ batch,
                            float* __restrict__ pool, float* __restrict__ cnt) {
  int wid = (blockIdx.x * blockDim.x + threadIdx.x) >> 6;
  int lane = threadIdx.x & 63;
  if (wid >= N) return;
  int start = rowptr[wid];
  int end = rowptr[wid + 1];

  // pass 1: max logit
  float m = -1e30f;
  for (int i = start + lane; i < end; i += 64) m = fmaxf(m, logit[i]);
  m = wave_reduce_max(m);

  // pass 2: sum of exp
  float ssum = 0.f;
  for (int i = start + lane; i < end; i += 64) ssum += expf(logit[i] - m);
  ssum = wave_reduce_sum(ssum);
  float inv = 1.0f / ssum;  // every node has >=1 edge (self-loop)

  // pass 3: weighted feature aggregate (wave-uniform edge loop, lane=feature)
  float acc = 0.f;
  for (int i = start; i < end; ++i) {
    int s = csrc[i];                       // wave-uniform -> broadcast
    float w = expf(logit[i] - m) * inv;    // wave-uniform
    acc += w * h[(size_t)s * 64 + lane];   // coalesced 256B row gather
  }
  float v = acc + bias[lane];
  v = (v > 0.f) ? v : (expm1f(v));  // ELU
  if (!do_pool) {
    out[(size_t)wid * 64 + lane] = v;
  } else {
    int g = batch[wid];
    atomicAdd(&pool[g * 64 + lane], v);
    if (lane == 0) atomicAdd(&cnt[g], 1.0f);
  }
}

// out[g] = (pool[g,:]/cnt[g]) . Wfc + bfc    (wave per graph)
__global__ void final_kernel(const float* __restrict__ pool, const float* __restrict__ cnt,
                             const float* __restrict__ Wfc, const float* __restrict__ bfc,
                             float* __restrict__ out, int G) {
  int wid = (blockIdx.x * blockDim.x + threadIdx.x) >> 6;
  int lane = threadIdx.x & 63;
  if (wid >= G) return;
  float c = fmaxf(cnt[wid], 1.0f);
  float v = pool[(size_t)wid * 64 + lane] * (1.0f / c) * Wfc[lane];
  v = wave_reduce_sum(v);
  if (lane == 0) out[wid] = v + bfc[0];
}

// ---------------------------------------------------------------------------

extern "C" void kernel_launch(void* const* d_in, const int* in_sizes, int n_in,
                              void* d_out, int out_size, void* d_ws, size_t ws_size,
                              hipStream_t stream) {
  const float* x     = (const float*)d_in[0];
  const int*   ei    = (const int*)d_in[1];
  const int*   batch = (const int*)d_in[2];
  const float* W1    = (const float*)d_in[3];
  const float* asrc1 = (const float*)d_in[4];
  const float* adst1 = (const float*)d_in[5];
  const float* b1    = (const float*)d_in[6];
  const float* W2    = (const float*)d_in[7];
  const float* asrc2 = (const float*)d_in[8];
  const float* adst2 = (const float*)d_in[9];
  const float* b2    = (const float*)d_in[10];
  const float* Wfc   = (const float*)d_in[11];
  const float* bfc   = (const float*)d_in[12];
  float* out = (float*)d_out;

  const int N = in_sizes[0] / 128;  // 100000
  const int E = in_sizes[1] / 2;    // 1600000
  const int G = 256;
  const int M = E + N;              // edges incl self-loops

  // workspace carve (256B aligned)
  char* p = (char*)d_ws;
  auto alloc = [&](size_t bytes) {
    char* r = p;
    p += (bytes + 255) & ~size_t(255);
    return r;
  };
  float* h1     = (float*)alloc((size_t)N * 64 * 4);
  float* h1e    = (float*)alloc((size_t)N * 64 * 4);
  float* h2     = h1;  // h1 dead after aggr1; alias
  float* alsrc  = (float*)alloc((size_t)N * 4);
  float* aldst  = (float*)alloc((size_t)N * 4);
  int*   deg    = (int*)alloc((size_t)N * 4);
  int*   rowptr = (int*)alloc((size_t)(N + 1) * 4);
  int*   cursor = (int*)alloc((size_t)N * 4);
  int*   csrc   = (int*)alloc((size_t)M * 4);
  int*   cdst   = (int*)alloc((size_t)M * 4);
  float* logit  = (float*)alloc((size_t)M * 4);
  float* pool   = (float*)alloc((size_t)G * 64 * 4);
  float* cnt    = (float*)alloc((size_t)G * 4);
  int*   partials = (int*)alloc(256 * 4);

  // ---- CSR build (shared by both layers) ----
  hipMemsetAsync(deg, 0, (size_t)N * 4, stream);
  deg_kernel<<<(M + 255) / 256, 256, 0, stream>>>(ei, E, N, deg);
  int nb = (N + 2047) / 2048;
  scan1_kernel<<<nb, 256, 0, stream>>>(deg, rowptr, partials, N);
  scan2_kernel<<<1, 64, 0, stream>>>(partials, nb, rowptr + N);
  scan3_kernel<<<(N + 255) / 256, 256, 0, stream>>>(rowptr, partials, N);
  hipMemcpyAsync(cursor, rowptr, (size_t)N * 4, hipMemcpyDeviceToDevice, stream);
  scatter_kernel<<<(M + 255) / 256, 256, 0, stream>>>(ei, E, N, cursor, csrc, cdst);

  // ---- layer 1 ----
  gemm64<128><<<(N + 63) / 64, 256, 0, stream>>>(x, W1, h1, N);
  al_kernel<<<(N * 64 + 255) / 256, 256, 0, stream>>>(h1, asrc1, adst1, alsrc, aldst, N);
  logits_kernel<<<(M + 255) / 256, 256, 0, stream>>>(csrc, cdst, alsrc, aldst, logit, M);
  aggr_kernel<<<(N * 64 + 255) / 256, 256, 0, stream>>>(rowptr, csrc, logit, h1, b1, h1e,
                                                        N, 0, nullptr, nullptr, nullptr);

  // ---- layer 2 (pooling fused into aggregation) ----
  gemm64<64><<<(N + 63) / 64, 256, 0, stream>>>(h1e, W2, h2, N);
  al_kernel<<<(N * 64 + 255) / 256, 256, 0, stream>>>(h2, asrc2, adst2, alsrc, aldst, N);
  logits_kernel<<<(M + 255) / 256, 256, 0, stream>>>(csrc, cdst, alsrc, aldst, logit, M);
  hipMemsetAsync(pool, 0, (size_t)G * 64 * 4, stream);
  hipMemsetAsync(cnt, 0, (size_t)G * 4, stream);
  aggr_kernel<<<(N * 64 + 255) / 256, 256, 0, stream>>>(rowptr, csrc, logit, h2, b2, nullptr,
                                                        N, 1, batch, pool, cnt);

  // ---- readout ----
  final_kernel<<<(G * 64 + 255) / 256, 256, 0, stream>>>(pool, cnt, Wfc, bfc, out, G);
}

// Round 2
// 935.953 us; speedup vs baseline: 1.1486x; 1.1486x over previous
//
#include <hip/hip_runtime.h>
#include <hip/hip_bf16.h>
#include <cstdint>

// ---------------------------------------------------------------------------
// GAT 2-layer model on MI355X.
// Pipeline:
//   CSR build (deg -> scan -> scatter)   [graph shared by both layers]
//   L1: gemm(x@W1) -> al -> logits -> aggr(+b1,ELU) -> h1e
//   L2: gemm(h1e@W2) -> al -> logits -> aggr(+b2,ELU, fused mean-pool accum)
//   final: pooled/cnt @ Wfc + bfc
// R1: aggr rewritten — register-cached edge data + online softmax.
//     Old version pointer-chased csrc[i] -> h[row] per edge (serial, ~500us).
//     New: coalesced chunk load of csrc/logit into registers (lane=edge),
//     one exp per edge total (parallel across lanes), shfl-broadcast in the
//     gather loop (no memory dependency), 4-way unrolled independent gathers.
// ---------------------------------------------------------------------------

__device__ __forceinline__ float wave_reduce_sum(float v) {
#pragma unroll
  for (int off = 32; off > 0; off >>= 1) v += __shfl_xor(v, off, 64);
  return v;
}
__device__ __forceinline__ float wave_reduce_max(float v) {
#pragma unroll
  for (int off = 32; off > 0; off >>= 1) v = fmaxf(v, __shfl_xor(v, off, 64));
  return v;
}

// ---------------- CSR build ----------------

__global__ void deg_kernel(const int* __restrict__ ei, int E, int N,
                           int* __restrict__ deg) {
  int t = blockIdx.x * blockDim.x + threadIdx.x;
  int total = E + N;
  if (t >= total) return;
  int d = (t < E) ? ei[E + t] : (t - E);  // self loops appended
  atomicAdd(&deg[d], 1);
}

// block scans 2048 elements (256 threads x 8)
__global__ void scan1_kernel(const int* __restrict__ deg, int* __restrict__ rowptr,
                             int* __restrict__ partials, int n) {
  __shared__ int wsum[4];
  int t = threadIdx.x;
  int lane = t & 63, wv = t >> 6;
  int base = blockIdx.x * 2048 + t * 8;
  int v[8];
  int s = 0;
#pragma unroll
  for (int i = 0; i < 8; i++) {
    int idx = base + i;
    v[i] = (idx < n) ? deg[idx] : 0;
    s += v[i];
  }
  int x = s;
#pragma unroll
  for (int off = 1; off < 64; off <<= 1) {
    int u = __shfl_up(x, off, 64);
    if (lane >= off) x += u;
  }
  if (lane == 63) wsum[wv] = x;
  __syncthreads();
  int woff = 0;
  for (int j = 0; j < wv; j++) woff += wsum[j];
  int excl = woff + x - s;
#pragma unroll
  for (int i = 0; i < 8; i++) {
    int idx = base + i;
    if (idx < n) rowptr[idx] = excl;
    excl += v[i];
  }
  if (t == 255) partials[blockIdx.x] = woff + x;  // block total
}

__global__ void scan2_kernel(int* __restrict__ partials, int nb,
                             int* __restrict__ rowptr_end) {
  if (threadIdx.x == 0 && blockIdx.x == 0) {
    int run = 0;
    for (int i = 0; i < nb; i++) {
      int t = partials[i];
      partials[i] = run;
      run += t;
    }
    *rowptr_end = run;
  }
}

__global__ void scan3_kernel(int* __restrict__ rowptr, const int* __restrict__ partials,
                             int n) {
  int idx = blockIdx.x * blockDim.x + threadIdx.x;
  if (idx < n) rowptr[idx] += partials[idx >> 11];
}

__global__ void scatter_kernel(const int* __restrict__ ei, int E, int N,
                               int* __restrict__ cursor, int* __restrict__ csrc,
                               int* __restrict__ cdst) {
  int t = blockIdx.x * blockDim.x + threadIdx.x;
  int total = E + N;
  if (t >= total) return;
  int s, d;
  if (t < E) {
    s = ei[t];
    d = ei[E + t];
  } else {
    s = d = t - E;
  }
  int pos = atomicAdd(&cursor[d], 1);
  csrc[pos] = s;
  cdst[pos] = d;
}

// ---------------- dense compute ----------------

// C[N][64] = A[N][KDIM] @ W[KDIM][64], fp32, 64x64 tile, 4x4 microtile
template <int KDIM>
__global__ __launch_bounds__(256) void gemm64(const float* __restrict__ A,
                                              const float* __restrict__ W,
                                              float* __restrict__ C, int N) {
  __shared__ float As[32][68];  // transposed: As[k][node]
  __shared__ float Ws[32][68];  // Ws[k][col]
  const int block_m = blockIdx.x * 64;
  const int t = threadIdx.x;  // 0..255
  const int tc = t & 15;      // col group
  const int tr = t >> 4;      // node group
  const int c0 = tc * 4, r0 = tr * 4;
  float acc[4][4] = {};

  for (int kc = 0; kc < KDIM; kc += 32) {
    for (int q = t; q < 512; q += 256) {
      int node = q >> 3, f4 = q & 7;
      int gn = block_m + node;
      if (gn >= N) gn = N - 1;  // clamp (stores are guarded)
      const float4 v = *(const float4*)(A + (size_t)gn * KDIM + kc + f4 * 4);
      As[f4 * 4 + 0][node] = v.x;
      As[f4 * 4 + 1][node] = v.y;
      As[f4 * 4 + 2][node] = v.z;
      As[f4 * 4 + 3][node] = v.w;
    }
    for (int q = t; q < 512; q += 256) {
      int k = q >> 4, f4 = q & 15;
      const float4 v = *(const float4*)(W + (size_t)(kc + k) * 64 + f4 * 4);
      *(float4*)&Ws[k][f4 * 4] = v;
    }
    __syncthreads();
#pragma unroll
    for (int k = 0; k < 32; ++k) {
      float4 a = *(const float4*)&As[k][r0];
      float4 b = *(const float4*)&Ws[k][c0];
      acc[0][0] += a.x * b.x; acc[0][1] += a.x * b.y; acc[0][2] += a.x * b.z; acc[0][3] += a.x * b.w;
      acc[1][0] += a.y * b.x; acc[1][1] += a.y * b.y; acc[1][2] += a.y * b.z; acc[1][3] += a.y * b.w;
      acc[2][0] += a.z * b.x; acc[2][1] += a.z * b.y; acc[2][2] += a.z * b.z; acc[2][3] += a.z * b.w;
      acc[3][0] += a.w * b.x; acc[3][1] += a.w * b.y; acc[3][2] += a.w * b.z; acc[3][3] += a.w * b.w;
    }
    __syncthreads();
  }
#pragma unroll
  for (int i = 0; i < 4; ++i) {
    int gn = block_m + r0 + i;
    if (gn < N) {
      float4 v = make_float4(acc[i][0], acc[i][1], acc[i][2], acc[i][3]);
      *(float4*)(C + (size_t)gn * 64 + c0) = v;
    }
  }
}

// al_src[n] = h[n,:] . a_src ; al_dst[n] = h[n,:] . a_dst   (wave per node)
__global__ void al_kernel(const float* __restrict__ h, const float* __restrict__ a_src,
                          const float* __restrict__ a_dst, float* __restrict__ alsrc,
                          float* __restrict__ aldst, int N) {
  int wid = (blockIdx.x * blockDim.x + threadIdx.x) >> 6;
  int lane = threadIdx.x & 63;
  if (wid >= N) return;
  float v = h[(size_t)wid * 64 + lane];
  float s1 = wave_reduce_sum(v * a_src[lane]);
  float s2 = wave_reduce_sum(v * a_dst[lane]);
  if (lane == 0) {
    alsrc[wid] = s1;
    aldst[wid] = s2;
  }
}

__global__ void logits_kernel(const int* __restrict__ csrc, const int* __restrict__ cdst,
                              const float* __restrict__ alsrc, const float* __restrict__ aldst,
                              float* __restrict__ logit, int M) {
  int t = blockIdx.x * blockDim.x + threadIdx.x;
  if (t >= M) return;
  float e = alsrc[csrc[t]] + aldst[cdst[t]];
  logit[t] = (e > 0.f) ? e : 0.2f * e;  // leaky_relu 0.2
}

// One wave per destination node. lane = feature AND edge-chunk slot.
// Online softmax: chunk of <=64 edges loaded coalesced into registers
// (lane i holds edge i's csrc/logit), exp computed once per edge in
// parallel, gather loop gets (s,w) via shfl — no load-dependent addresses.
__global__ void aggr_kernel(const int* __restrict__ rowptr, const int* __restrict__ csrc,
                            const float* __restrict__ logit, const float* __restrict__ h,
                            const float* __restrict__ bias, float* __restrict__ out,
                            int N, int do_pool, const int* __restrict__ batch,
                            float* __restrict__ pool, float* __restrict__ cnt) {
  int wid = (blockIdx.x * blockDim.x + threadIdx.x) >> 6;
  int lane = threadIdx.x & 63;
  if (wid >= N) return;
  int start = rowptr[wid];
  int end = rowptr[wid + 1];

  float m = -1e30f;   // running max
  float ssum = 0.f;   // running sum of exp (relative to m)
  float acc = 0.f;    // running weighted feature sum (relative to m)

  for (int cbase = start; cbase < end; cbase += 64) {
    int i = cbase + lane;
    bool valid = i < end;
    float lg = valid ? logit[i] : -1e30f;  // coalesced chunk load
    int   s  = valid ? csrc[i] : 0;        // coalesced chunk load
    int   cc = min(end - cbase, 64);

    float cmax = wave_reduce_max(lg);
    float newm = fmaxf(m, cmax);
    float scale = __expf(m - newm);        // m=-1e30 first chunk -> 0; fine
    float w = valid ? __expf(lg - newm) : 0.f;
    ssum = ssum * scale + wave_reduce_sum(w);
    acc *= scale;
    m = newm;

    // gather loop: s/w broadcast from registers, loads independent
    float a0 = 0.f, a1 = 0.f, a2 = 0.f, a3 = 0.f;
    int j = 0;
    for (; j + 4 <= cc; j += 4) {
      int   s0 = __shfl(s, j),     s1 = __shfl(s, j + 1);
      int   s2 = __shfl(s, j + 2), s3 = __shfl(s, j + 3);
      float w0 = __shfl(w, j),     w1 = __shfl(w, j + 1);
      float w2 = __shfl(w, j + 2), w3 = __shfl(w, j + 3);
      a0 += w0 * h[(size_t)s0 * 64 + lane];
      a1 += w1 * h[(size_t)s1 * 64 + lane];
      a2 += w2 * h[(size_t)s2 * 64 + lane];
      a3 += w3 * h[(size_t)s3 * 64 + lane];
    }
    for (; j < cc; ++j) {
      int   sj = __shfl(s, j);
      float wj = __shfl(w, j);
      a0 += wj * h[(size_t)sj * 64 + lane];
    }
    acc += (a0 + a1) + (a2 + a3);
  }

  float v = acc / ssum + bias[lane];       // ssum >= 1 (self-loop)
  v = (v > 0.f) ? v : expm1f(v);           // ELU
  if (!do_pool) {
    out[(size_t)wid * 64 + lane] = v;
  } else {
    int g = batch[wid];
    atomicAdd(&pool[g * 64 + lane], v);
    if (lane == 0) atomicAdd(&cnt[g], 1.0f);
  }
}

// out[g] = (pool[g,:]/cnt[g]) . Wfc + bfc    (wave per graph)
__global__ void final_kernel(const float* __restrict__ pool, const float* __restrict__ cnt,
                             const float* __restrict__ Wfc, const float* __restrict__ bfc,
                             float* __restrict__ out, int G) {
  int wid = (blockIdx.x * blockDim.x + threadIdx.x) >> 6;
  int lane = threadIdx.x & 63;
  if (wid >= G) return;
  float c = fmaxf(cnt[wid], 1.0f);
  float v = pool[(size_t)wid * 64 + lane] * (1.0f / c) * Wfc[lane];
  v = wave_reduce_sum(v);
  if (lane == 0) out[wid] = v + bfc[0];
}

// ---------------------------------------------------------------------------

extern "C" void kernel_launch(void* const* d_in, const int* in_sizes, int n_in,
                              void* d_out, int out_size, void* d_ws, size_t ws_size,
                              hipStream_t stream) {
  const float* x     = (const float*)d_in[0];
  const int*   ei    = (const int*)d_in[1];
  const int*   batch = (const int*)d_in[2];
  const float* W1    = (const float*)d_in[3];
  const float* asrc1 = (const float*)d_in[4];
  const float* adst1 = (const float*)d_in[5];
  const float* b1    = (const float*)d_in[6];
  const float* W2    = (const float*)d_in[7];
  const float* asrc2 = (const float*)d_in[8];
  const float* adst2 = (const float*)d_in[9];
  const float* b2    = (const float*)d_in[10];
  const float* Wfc   = (const float*)d_in[11];
  const float* bfc   = (const float*)d_in[12];
  float* out = (float*)d_out;

  const int N = in_sizes[0] / 128;  // 100000
  const int E = in_sizes[1] / 2;    // 1600000
  const int G = 256;
  const int M = E + N;              // edges incl self-loops

  // workspace carve (256B aligned)
  char* p = (char*)d_ws;
  auto alloc = [&](size_t bytes) {
    char* r = p;
    p += (bytes + 255) & ~size_t(255);
    return r;
  };
  float* h1     = (float*)alloc((size_t)N * 64 * 4);
  float* h1e    = (float*)alloc((size_t)N * 64 * 4);
  float* h2     = h1;  // h1 dead after aggr1; alias
  float* alsrc  = (float*)alloc((size_t)N * 4);
  float* aldst  = (float*)alloc((size_t)N * 4);
  int*   deg    = (int*)alloc((size_t)N * 4);
  int*   rowptr = (int*)alloc((size_t)(N + 1) * 4);
  int*   cursor = (int*)alloc((size_t)N * 4);
  int*   csrc   = (int*)alloc((size_t)M * 4);
  int*   cdst   = (int*)alloc((size_t)M * 4);
  float* logit  = (float*)alloc((size_t)M * 4);
  float* pool   = (float*)alloc((size_t)G * 64 * 4);
  float* cnt    = (float*)alloc((size_t)G * 4);
  int*   partials = (int*)alloc(256 * 4);

  // ---- CSR build (shared by both layers) ----
  hipMemsetAsync(deg, 0, (size_t)N * 4, stream);
  deg_kernel<<<(M + 255) / 256, 256, 0, stream>>>(ei, E, N, deg);
  int nb = (N + 2047) / 2048;
  scan1_kernel<<<nb, 256, 0, stream>>>(deg, rowptr, partials, N);
  scan2_kernel<<<1, 64, 0, stream>>>(partials, nb, rowptr + N);
  scan3_kernel<<<(N + 255) / 256, 256, 0, stream>>>(rowptr, partials, N);
  hipMemcpyAsync(cursor, rowptr, (size_t)N * 4, hipMemcpyDeviceToDevice, stream);
  scatter_kernel<<<(M + 255) / 256, 256, 0, stream>>>(ei, E, N, cursor, csrc, cdst);

  // ---- layer 1 ----
  gemm64<128><<<(N + 63) / 64, 256, 0, stream>>>(x, W1, h1, N);
  al_kernel<<<(N * 64 + 255) / 256, 256, 0, stream>>>(h1, asrc1, adst1, alsrc, aldst, N);
  logits_kernel<<<(M + 255) / 256, 256, 0, stream>>>(csrc, cdst, alsrc, aldst, logit, M);
  aggr_kernel<<<(N * 64 + 255) / 256, 256, 0, stream>>>(rowptr, csrc, logit, h1, b1, h1e,
                                                        N, 0, nullptr, nullptr, nullptr);

  // ---- layer 2 (pooling fused into aggregation) ----
  gemm64<64><<<(N + 63) / 64, 256, 0, stream>>>(h1e, W2, h2, N);
  al_kernel<<<(N * 64 + 255) / 256, 256, 0, stream>>>(h2, asrc2, adst2, alsrc, aldst, N);
  logits_kernel<<<(M + 255) / 256, 256, 0, stream>>>(csrc, cdst, alsrc, aldst, logit, M);
  hipMemsetAsync(pool, 0, (size_t)G * 64 * 4, stream);
  hipMemsetAsync(cnt, 0, (size_t)G * 4, stream);
  aggr_kernel<<<(N * 64 + 255) / 256, 256, 0, stream>>>(rowptr, csrc, logit, h2, b2, nullptr,
                                                        N, 1, batch, pool, cnt);

  // ---- readout ----
  final_kernel<<<(G * 64 + 255) / 256, 256, 0, stream>>>(pool, cnt, Wfc, bfc, out, G);
}